// Round 19
// baseline (400.906 us; speedup 1.0000x reference)
//
#include <hip/hip_runtime.h>
#include <stdint.h>

// LiquidStateMachine on MI355X — round 19.
// r18 post-mortem: bank-phase rotation failed its discriminator (conflicts
// -6% vs predicted -45%, dur unchanged) -> lsm_main is at its structural
// plateau ~264us (VALU ~52%, LDS ~55%, residual = unhidable latency at
// 2 waves/SIMD; 7 attacks r12-r18 all neutral except the fma_mix cut).
// r19 attacks the remaining 62us prep gap (total 326 - main 264):
//   - drop the rotation (neutral) -> single-pass fill;
//   - ROW-parallel coalesced fill: one block per k row, 64 lanes sweep 512
//     cols in 8 coalesced 256B reads; slot via global atomic cursor per
//     column (r3-proven). Old fill read W column-wise = 64 lines/instr.
// lsm_main byte-identical to r18 (f16 spikes @16k, v_fma_mix, 2-deep
// pipeline, ping-pong bufs, coalesced pro/epilogue).
// Weights EXACT fp32 (r2: rounding flips spikes); f16 spike 0/1 exact.
//
// d_ws layout (bytes):
//   0      PERM[512]  sorted-rank -> column
//   2048   RANK[512]  column -> sorted rank
//   4096   CNT[512]   nnz per column          (zeroed via hipMemsetAsync)
//   6144   CTR[512]   fill cursors            (zeroed via hipMemsetAsync)
//   8192   CNTW[8]    per-group padded trip count (multiple of 8)
//   8256   IBASE[8]   per-group byte base into IDX region
//   8320   WBASE[8]   per-group byte base into WT region
//   16384  IDX        u16 spike-offset (16k):
//                     byte = ib + (j>>3)*1024 + lane*16 + (j&7)*2
//   81920  WT         f32 w: byte = wb + (j>>3)*2048 + lane*32 + (j&7)*4

#define N_NEU 512
#define B_ROWS 2048
#define D_IN 256
#define R_PB 8
#define NBLK (B_ROWS / R_PB)   // 256 blocks x 512 threads = 1 block/CU

#define WS_PERM    0
#define WS_RANK    2048
#define WS_CNT     4096
#define WS_CTR     6144
#define WS_CNTW    8192
#define WS_IBASE   8256
#define WS_WBASE   8320
#define WS_IDX     16384
#define WS_WT      81920

// spike record: 16 bytes (8 rows x f16 0/1) at natural offset 16k
#define SPK_OFF(k)  ((k) << 4)
#define SPK_BUF     8192       // one buffer: 512 neurons x 16 B

#define H16_ONE 0x3C00u        // f16 1.0

// ---------------------------------------------------------------- prep A
__global__ __launch_bounds__(256) void lsm_count(
    const float* __restrict__ W, uint32_t* __restrict__ ws)
{
    int t  = threadIdx.x;
    int k0 = blockIdx.x * 4;
    int c0 = 0, c1 = 0;
    #pragma unroll
    for (int kk = 0; kk < 4; ++kk) {
        const float* row = W + (size_t)(k0 + kk) * N_NEU;
        c0 += (row[t]       != 0.0f) ? 1 : 0;
        c1 += (row[t + 256] != 0.0f) ? 1 : 0;
    }
    if (c0) atomicAdd(&ws[(WS_CNT >> 2) + t],       (uint32_t)c0);
    if (c1) atomicAdd(&ws[(WS_CNT >> 2) + t + 256], (uint32_t)c1);
}

// ---------------------------------------------------------------- prep B
__global__ __launch_bounds__(512) void lsm_sort(uint32_t* __restrict__ ws)
{
    __shared__ int hist[N_NEU + 1];
    __shared__ int csort[N_NEU];
    __shared__ int gcw[8];

    int t = threadIdx.x;
    int creal = (int)ws[(WS_CNT >> 2) + t];
    for (int i = t; i < N_NEU + 1; i += 512) hist[i] = 0;
    __syncthreads();
    atomicAdd(&hist[creal], 1);
    __syncthreads();
    if (t == 0) {
        int acc = 0;
        for (int v = 0; v <= N_NEU; ++v) { int h = hist[v]; hist[v] = acc; acc += h; }
    }
    __syncthreads();
    int rank = atomicAdd(&hist[creal], 1);
    ws[(WS_PERM >> 2) + rank] = (uint32_t)t;
    ws[(WS_RANK >> 2) + t]    = (uint32_t)rank;
    csort[rank] = creal;
    __syncthreads();
    if (t < 8) {
        int cw = csort[t * 64 + 63];         // ascending -> group max is last
        cw = (cw + 7) & ~7;                  // pad to multiple of 8 (one chunk)
        gcw[t] = cw;
        ws[(WS_CNTW >> 2) + t] = (uint32_t)cw;
    }
    __syncthreads();
    if (t == 0) {
        int ai = 0, aw = 0;
        for (int g = 0; g < 8; ++g) {
            ws[(WS_IBASE >> 2) + g] = (uint32_t)ai;
            ws[(WS_WBASE >> 2) + g] = (uint32_t)aw;
            ai += gcw[g] * 64 * 2;           // bytes (u16 per entry)
            aw += gcw[g] * 64 * 4;           // bytes (f32 per entry)
        }
    }
    __syncthreads();
    // pad tail slots of this thread's column (offset 0 -> neuron 0's record,
    // w=0.0f -> harmless; same-address across lanes -> broadcast, no conflict)
    int wg = rank >> 6, ls = rank & 63;
    int cw = gcw[wg];
    uint32_t ib = ws[(WS_IBASE >> 2) + wg];
    uint32_t wb = ws[(WS_WBASE >> 2) + wg];
    char* base = (char*)ws;
    for (int j = creal; j < cw; ++j) {
        *(unsigned short*)(base + WS_IDX + ib + (j >> 3) * 1024 + ls * 16 + (j & 7) * 2) = 0;
        *(float*)(base + WS_WT + wb + (j >> 3) * 2048 + ls * 32 + (j & 7) * 4) = 0.0f;
    }
}

// ---------------------------------------------------------------- prep C
// One block per K-ROW: 64 lanes sweep 512 columns in 8 coalesced 256B
// reads. Slot via global atomic cursor per column (order irrelevant).
__global__ __launch_bounds__(64) void lsm_fill(
    const float* __restrict__ W, uint32_t* __restrict__ ws)
{
    int k    = blockIdx.x;
    int lane = threadIdx.x;
    char* base = (char*)ws;
    const float* row = W + (size_t)k * N_NEU;
    unsigned short koff = (unsigned short)SPK_OFF(k);
    #pragma unroll
    for (int i = 0; i < N_NEU / 64; ++i) {
        int c = lane + i * 64;
        float wv = row[c];
        if (wv != 0.0f) {
            uint32_t rank = ws[(WS_RANK >> 2) + c];
            int wg = (int)(rank >> 6), ls = (int)(rank & 63);
            uint32_t ib = ws[(WS_IBASE >> 2) + wg];
            uint32_t wb = ws[(WS_WBASE >> 2) + wg];
            int j = (int)atomicAdd(&ws[(WS_CTR >> 2) + c], 1u);
            *(unsigned short*)(base + WS_IDX + ib + (j >> 3) * 1024 + ls * 16 + (j & 7) * 2)
                = koff;
            *(float*)(base + WS_WT + wb + (j >> 3) * 2048 + ls * 32 + (j & 7) * 4) = wv;
        }
    }
}

// -------- spill-proof pipeline macros (all scalars, no arrays/fns) --------
// B = spike-buffer base for this step; offsets pre-scaled to 16k.
#define GATH(P, X, B) \
    P##0 = *(const uint4*)((B) + ((X).x & 0xffffu)); \
    P##1 = *(const uint4*)((B) + ((X).x >> 16));     \
    P##2 = *(const uint4*)((B) + ((X).y & 0xffffu)); \
    P##3 = *(const uint4*)((B) + ((X).y >> 16));     \
    P##4 = *(const uint4*)((B) + ((X).z & 0xffffu)); \
    P##5 = *(const uint4*)((B) + ((X).z >> 16));     \
    P##6 = *(const uint4*)((B) + ((X).w & 0xffffu)); \
    P##7 = *(const uint4*)((B) + ((X).w >> 16));

// mixed-precision FMA: acc(f32) += w(f32) * f16 half of S (lo/hi)
#define FMIX_LO(ACC, WV, S) \
    asm("v_fma_mix_f32 %0, %1, %2, %0 op_sel:[0,0,0] op_sel_hi:[0,1,0]" \
        : "+v"(ACC) : "v"(WV), "v"(S));
#define FMIX_HI(ACC, WV, S) \
    asm("v_fma_mix_f32 %0, %1, %2, %0 op_sel:[0,1,0] op_sel_hi:[0,1,0]" \
        : "+v"(ACC) : "v"(WV), "v"(S));

// one entry: weight WV x 8 rows' f16 spikes (uint4 S = 4 f16-pairs)
#define C1(S, WV) \
    FMIX_LO(rec0, WV, (S).x) FMIX_HI(rec1, WV, (S).x) \
    FMIX_LO(rec2, WV, (S).y) FMIX_HI(rec3, WV, (S).y) \
    FMIX_LO(rec4, WV, (S).z) FMIX_HI(rec5, WV, (S).z) \
    FMIX_LO(rec6, WV, (S).w) FMIX_HI(rec7, WV, (S).w)

#define CONS(P, WA, WB) \
    C1(P##0, (WA).x) C1(P##1, (WA).y) C1(P##2, (WA).z) C1(P##3, (WA).w) \
    C1(P##4, (WB).x) C1(P##5, (WB).y) C1(P##6, (WB).z) C1(P##7, (WB).w)

#define LDW(WA, WB, K) \
    WA = ((const float4*)(wp0 + (K) * 2048))[0]; \
    WB = ((const float4*)(wp0 + (K) * 2048))[1];

// ---------------------------------------------------------------- main
// LDS map:
//   [0,8192)       spk buffer 0 (f16 x 8 rows per neuron, 16B @ 16k)
//   [8192,16384)   spk buffer 1 (ping-pong)
//   [16384,32768)  stg: 16KB scratch — state staging / rates rl / out staging
__global__ __launch_bounds__(512, 1)
void lsm_main(
    const float* __restrict__ rates, const float* __restrict__ inW,
    const float* __restrict__ vin,   const float* __restrict__ cin,
    const int* __restrict__ nsteps_p,
    const uint32_t* __restrict__ ws, float* __restrict__ out)
{
    __shared__ __align__(16) unsigned char smem[2 * SPK_BUF + 16384];
    float* stg = (float*)(smem + 2 * SPK_BUF);
    float* rl  = stg;

    int q    = threadIdx.x;
    int blk  = blockIdx.x;
    int r0   = blk * R_PB;
    int w    = q >> 6;
    int lane = q & 63;
    // SIMD balance: waves {s, s+4} share SIMD s; give them groups {s, 7-s}
    int wg   = (w < 4) ? w : (11 - w);
    int n    = (int)ws[(WS_PERM >> 2) + wg * 64 + lane];
    int cw   = (int)ws[(WS_CNTW >> 2) + wg];     // wave-uniform
    int nit  = cw >> 3;                          // 8-entry chunks (<=12)
    const char* ip0 = (const char*)ws + WS_IDX + ws[(WS_IBASE >> 2) + wg]
                    + lane * 16;
    const char* wp0 = (const char*)ws + WS_WT  + ws[(WS_WBASE >> 2) + wg]
                    + lane * 32;
    int spk_n = SPK_OFF(n);                      // this column's record

    // ---- coalesced state staging: cin then vin through LDS ----
    float c0v[R_PB], v0v[R_PB];
    #pragma unroll
    for (int r = 0; r < R_PB; ++r)
        stg[r * N_NEU + q] = cin[(size_t)(r0 + r) * N_NEU + q];   // coalesced
    __syncthreads();
    #pragma unroll
    for (int r = 0; r < R_PB; ++r) c0v[r] = stg[r * N_NEU + n];
    __syncthreads();
    #pragma unroll
    for (int r = 0; r < R_PB; ++r)
        stg[r * N_NEU + q] = vin[(size_t)(r0 + r) * N_NEU + q];   // coalesced
    __syncthreads();
    #pragma unroll
    for (int r = 0; r < R_PB; ++r) v0v[r] = stg[r * N_NEU + n];
    __syncthreads();

    // ---- rates -> rl (coalesced), then I-dot ----
    ((float4*)rl)[q] = ((const float4*)(rates + (size_t)r0 * D_IN))[q];
    __syncthreads();

    float I[R_PB] = {0.f, 0.f, 0.f, 0.f, 0.f, 0.f, 0.f, 0.f};
    {
        const float4* wrow = (const float4*)(inW + (size_t)n * D_IN);
        for (int d4 = 0; d4 < D_IN / 4; ++d4) {
            float4 wv = wrow[d4];
            #pragma unroll
            for (int r = 0; r < R_PB; ++r) {
                const float* rr = rl + r * D_IN + d4 * 4;   // LDS broadcast
                I[r] += wv.x * rr[0] + wv.y * rr[1] + wv.z * rr[2] + wv.w * rr[3];
            }
        }
    }

    // initial f16 spikes -> buffer 0
    uint4 sini = make_uint4(0u, 0u, 0u, 0u);
    #pragma unroll
    for (int r = 0; r < R_PB; ++r) {
        unsigned hb = (c0v[r] > 0.f) ? H16_ONE : 0u;
        unsigned sh = (r & 1) ? 16 : 0;
        if (r < 2)      sini.x |= hb << sh;
        else if (r < 4) sini.y |= hb << sh;
        else if (r < 6) sini.z |= hb << sh;
        else            sini.w |= hb << sh;
    }
    *(uint4*)(smem + spk_n) = sini;

    // packed spike counters: byte r = count of (v>0) for row r (<=64, fits)
    unsigned ssx = 0u, ssy = 0u;

    // preload ENTIRE index stream into registers (constant across steps)
    uint4 xr0, xr1, xr2, xr3, xr4, xr5, xr6, xr7, xr8, xr9, xr10, xr11;
    const uint4 xz = make_uint4(0u, 0u, 0u, 0u);
    xr0  =              *(const uint4*)(ip0);
    xr1  = (1  < nit) ? *(const uint4*)(ip0 + 1024)  : xz;
    xr2  = (2  < nit) ? *(const uint4*)(ip0 + 2048)  : xz;
    xr3  = (3  < nit) ? *(const uint4*)(ip0 + 3072)  : xz;
    xr4  = (4  < nit) ? *(const uint4*)(ip0 + 4096)  : xz;
    xr5  = (5  < nit) ? *(const uint4*)(ip0 + 5120)  : xz;
    xr6  = (6  < nit) ? *(const uint4*)(ip0 + 6144)  : xz;
    xr7  = (7  < nit) ? *(const uint4*)(ip0 + 7168)  : xz;
    xr8  = (8  < nit) ? *(const uint4*)(ip0 + 8192)  : xz;
    xr9  = (9  < nit) ? *(const uint4*)(ip0 + 9216)  : xz;
    xr10 = (10 < nit) ? *(const uint4*)(ip0 + 10240) : xz;
    xr11 = (11 < nit) ? *(const uint4*)(ip0 + 11264) : xz;

    const float AS   = (float)0.8187307530779818;   // exp(-1/5)
    const float OMAS = (float)(1.0 - 0.8187307530779818);
    const float AM   = (float)0.9512294245007140;   // exp(-1/20)
    const float OMAM = (float)(1.0 - 0.9512294245007140);

    int T = nsteps_p[0];
    __syncthreads();   // initial spikes visible

    #pragma unroll 1
    for (int t = 0; t < T; ++t) {
        const unsigned char* sb = smem + ((t & 1) ? SPK_BUF : 0);   // read buf
        unsigned char*       db = smem + ((t & 1) ? 0 : SPK_BUF);   // write buf

        float rec0 = 0.f, rec1 = 0.f, rec2 = 0.f, rec3 = 0.f;
        float rec4 = 0.f, rec5 = 0.f, rec6 = 0.f, rec7 = 0.f;
        uint4 a0, a1, a2, a3, a4, a5, a6, a7;
        uint4 b0, b1, b2, b3, b4, b5, b6, b7;
        float4 waA, wbA, waB, wbB;

        // 2-deep pipeline: gather addrs from registers, weights 2-deep.
        LDW(waA, wbA, 0)
        GATH(a, xr0, sb)
        if (1 < nit)  { LDW(waB, wbB, 1)  GATH(b, xr1, sb)  }
        CONS(a, waA, wbA)
        if (1 < nit)  {
            if (2 < nit)  { LDW(waA, wbA, 2)  GATH(a, xr2, sb)  }
            CONS(b, waB, wbB)
        }
        if (2 < nit)  {
            if (3 < nit)  { LDW(waB, wbB, 3)  GATH(b, xr3, sb)  }
            CONS(a, waA, wbA)
        }
        if (3 < nit)  {
            if (4 < nit)  { LDW(waA, wbA, 4)  GATH(a, xr4, sb)  }
            CONS(b, waB, wbB)
        }
        if (4 < nit)  {
            if (5 < nit)  { LDW(waB, wbB, 5)  GATH(b, xr5, sb)  }
            CONS(a, waA, wbA)
        }
        if (5 < nit)  {
            if (6 < nit)  { LDW(waA, wbA, 6)  GATH(a, xr6, sb)  }
            CONS(b, waB, wbB)
        }
        if (6 < nit)  {
            if (7 < nit)  { LDW(waB, wbB, 7)  GATH(b, xr7, sb)  }
            CONS(a, waA, wbA)
        }
        if (7 < nit)  {
            if (8 < nit)  { LDW(waA, wbA, 8)  GATH(a, xr8, sb)  }
            CONS(b, waB, wbB)
        }
        if (8 < nit)  {
            if (9 < nit)  { LDW(waB, wbB, 9)  GATH(b, xr9, sb)  }
            CONS(a, waA, wbA)
        }
        if (9 < nit)  {
            if (10 < nit) { LDW(waA, wbA, 10) GATH(a, xr10, sb) }
            CONS(b, waB, wbB)
        }
        if (10 < nit) {
            if (11 < nit) { LDW(waB, wbB, 11) GATH(b, xr11, sb) }
            CONS(a, waA, wbA)
        }
        if (11 < nit) {
            CONS(b, waB, wbB)
        }

        // update; write new f16 spikes to the other buffer (no WAR hazard)
        uint4 ns = make_uint4(0u, 0u, 0u, 0u);
        unsigned vbx = 0u, vby = 0u;
        {
            float rca[R_PB] = {rec0, rec1, rec2, rec3, rec4, rec5, rec6, rec7};
            #pragma unroll
            for (int r = 0; r < R_PB; ++r) {
                c0v[r] = AS * c0v[r] + OMAS * (I[r] + rca[r]);
                v0v[r] = AM * v0v[r] + OMAM * c0v[r];
                unsigned hb = (c0v[r] > 0.f) ? H16_ONE : 0u;
                unsigned vb = (v0v[r] > 0.f) ? 1u : 0u;
                unsigned sh = (r & 1) ? 16 : 0;
                if (r < 2)      ns.x |= hb << sh;
                else if (r < 4) ns.y |= hb << sh;
                else if (r < 6) ns.z |= hb << sh;
                else            ns.w |= hb << sh;
                if (r < 4) vbx |= vb << (r * 8);
                else       vby |= vb << ((r - 4) * 8);
            }
        }
        ssx += vbx;   // bytewise counters, max 64 < 256: no inter-byte carry
        ssy += vby;
        *(uint4*)(db + spk_n) = ns;
        __syncthreads();   // new spikes visible; old buffer free for reuse
    }

    // ---- coalesced epilogue: stage each quantity through LDS ----
    float invT = 1.0f / (float)T;
    size_t BN = (size_t)B_ROWS * N_NEU;

    #pragma unroll
    for (int r = 0; r < R_PB; ++r) {
        unsigned cnt = (r < 4) ? ((ssx >> (r * 8)) & 0xffu)
                               : ((ssy >> ((r - 4) * 8)) & 0xffu);
        stg[r * N_NEU + n] = (float)cnt * invT;
    }
    __syncthreads();
    #pragma unroll
    for (int r = 0; r < R_PB; ++r)
        out[(size_t)(r0 + r) * N_NEU + q] = stg[r * N_NEU + q];   // coalesced
    __syncthreads();

    #pragma unroll
    for (int r = 0; r < R_PB; ++r) stg[r * N_NEU + n] = v0v[r];
    __syncthreads();
    #pragma unroll
    for (int r = 0; r < R_PB; ++r)
        out[BN + (size_t)(r0 + r) * N_NEU + q] = stg[r * N_NEU + q];
    __syncthreads();

    #pragma unroll
    for (int r = 0; r < R_PB; ++r) stg[r * N_NEU + n] = c0v[r];
    __syncthreads();
    #pragma unroll
    for (int r = 0; r < R_PB; ++r)
        out[2 * BN + (size_t)(r0 + r) * N_NEU + q] = stg[r * N_NEU + q];
}

// ---------------------------------------------------------------- launch
extern "C" void kernel_launch(void* const* d_in, const int* in_sizes, int n_in,
                              void* d_out, int out_size, void* d_ws, size_t ws_size,
                              hipStream_t stream)
{
    const float* rates = (const float*)d_in[0];
    const float* inW   = (const float*)d_in[1];
    const float* W     = (const float*)d_in[2];
    const float* vin   = (const float*)d_in[3];
    const float* cin   = (const float*)d_in[4];
    const int*   nst   = (const int*)d_in[5];
    uint32_t* ws = (uint32_t*)d_ws;
    float* out = (float*)d_out;
    (void)in_sizes; (void)n_in; (void)out_size; (void)ws_size;

    // zero CNT + CTR (harness poisons d_ws to 0xAA before every call)
    hipMemsetAsync((char*)d_ws + WS_CNT, 0, 4096, stream);

    lsm_count<<<128, 256, 0, stream>>>(W, ws);
    lsm_sort<<<1, 512, 0, stream>>>(ws);
    lsm_fill<<<N_NEU, 64, 0, stream>>>(W, ws);
    lsm_main<<<NBLK, 512, 0, stream>>>(rates, inW, vin, cin, nst, ws, out);
}